// Round 1
// baseline (272.865 us; speedup 1.0000x reference)
//
#include <hip/hip_runtime.h>
#include <stdint.h>

#define OUT_F   2048
#define IN_BASE 2048
#define N_EMB   64
#define IN_TOT  2176   // 2048 + 128
#define NNZ_W   400000
#define NNZ_B   1024
#define BATCH   8192

typedef __bf16 bf16x8 __attribute__((ext_vector_type(8)));
typedef __bf16 bf16x4 __attribute__((ext_vector_type(4)));
typedef float  floatx4 __attribute__((ext_vector_type(4)));

// ---------------------------------------------------------------------------
// Kernel 1: build x_ext in bf16.  x_ext[b, 0:2048] = x, then
//   x_ext[b, 2048+j] = e0v[j] * x[b, e0p[j]]
//   x_ext[b, 2112+j] = e1v[j] * x_ext[b, e1p[j]]   (e1p < 2112)
// Each thread handles 4 consecutive columns of one batch row.
// ---------------------------------------------------------------------------
__global__ void __launch_bounds__(256) build_x_kernel(
    const float* __restrict__ x,
    const float* __restrict__ e0v, const int* __restrict__ e0p,
    const float* __restrict__ e1v, const int* __restrict__ e1p,
    __bf16* __restrict__ xb)
{
    const int GROUPS = IN_TOT / 4;                 // 544 groups per row
    int gid = blockIdx.x * 256 + threadIdx.x;      // grid sized exactly
    int b = gid / GROUPS;
    int g = gid - b * GROUPS;
    const float* xr = x + (size_t)b * IN_BASE;

    float v[4];
    if (g < IN_BASE / 4) {
        const float4 t = *(const float4*)(xr + g * 4);
        v[0] = t.x; v[1] = t.y; v[2] = t.z; v[3] = t.w;
    } else if (g < (IN_BASE + N_EMB) / 4) {        // embed0: cols 2048..2111
        int j = (g - IN_BASE / 4) * 4;
#pragma unroll
        for (int t = 0; t < 4; t++) v[t] = e0v[j + t] * xr[e0p[j + t]];
    } else {                                       // embed1: cols 2112..2175
        int j = (g - (IN_BASE + N_EMB) / 4) * 4;
#pragma unroll
        for (int t = 0; t < 4; t++) {
            int p = e1p[j + t];
            float base = (p < IN_BASE) ? xr[p]
                                       : e0v[p - IN_BASE] * xr[e0p[p - IN_BASE]];
            v[t] = e1v[j + t] * base;
        }
    }
    bf16x4 o;
    o[0] = (__bf16)v[0]; o[1] = (__bf16)v[1]; o[2] = (__bf16)v[2]; o[3] = (__bf16)v[3];
    *(bf16x4*)(xb + (size_t)b * IN_TOT + g * 4) = o;
}

// ---------------------------------------------------------------------------
// Kernel 2: COO scatter-add into zeroed fp32 W  (duplicates sum in fp32)
// ---------------------------------------------------------------------------
__global__ void __launch_bounds__(256) scatter_w_kernel(
    const float* __restrict__ vals, const int* __restrict__ rows,
    const int* __restrict__ cols, float* __restrict__ W)
{
    int i = blockIdx.x * 256 + threadIdx.x;
    if (i < NNZ_W)
        atomicAdd(W + (size_t)rows[i] * IN_TOT + cols[i], vals[i]);
}

// ---------------------------------------------------------------------------
// Kernel 3: W fp32 -> bf16
// ---------------------------------------------------------------------------
__global__ void __launch_bounds__(256) w_to_bf16_kernel(
    const float* __restrict__ Wf, __bf16* __restrict__ Wb)
{
    int e = (blockIdx.x * 256 + threadIdx.x) * 4;  // total elems divisible by 4
    const float4 t = *(const float4*)(Wf + e);
    bf16x4 o;
    o[0] = (__bf16)t.x; o[1] = (__bf16)t.y; o[2] = (__bf16)t.z; o[3] = (__bf16)t.w;
    *(bf16x4*)(Wb + e) = o;
}

// ---------------------------------------------------------------------------
// Kernel 4: bias scatter-add into zeroed fp32 b
// ---------------------------------------------------------------------------
__global__ void __launch_bounds__(256) scatter_b_kernel(
    const float* __restrict__ vals, const int* __restrict__ idx,
    float* __restrict__ b)
{
    int i = blockIdx.x * 256 + threadIdx.x;
    if (i < NNZ_B) atomicAdd(b + idx[i], vals[i]);
}

// ---------------------------------------------------------------------------
// Kernel 5: GEMM  C[M,N] = A[M,K] * W[N,K]^T + bias   (all K-major, "NT")
// m97 structure: 128x128 block tile, 4 waves, 64x64 per wave (4x4 MFMA grid),
// BK=64, global_load_lds width=16 staging, single-buffered LDS.
// ---------------------------------------------------------------------------
#define BM 128
#define BN 128
#define BK 64

__global__ void __launch_bounds__(256) gemm_kernel(
    const __bf16* __restrict__ A,   // [BATCH][IN_TOT]
    const __bf16* __restrict__ W,   // [OUT_F][IN_TOT]
    const float*  __restrict__ bias,
    float* __restrict__ C)          // [BATCH][OUT_F]
{
    __shared__ __bf16 sA[BM * BK];  // row-major [row][k], 128 B per row
    __shared__ __bf16 sB[BN * BK];

    const int tid  = threadIdx.x;
    const int bm   = blockIdx.x;    // M tile (64 tiles)
    const int bn   = blockIdx.y;    // N tile (16 tiles)
    const int wave = tid >> 6;
    const int lane = tid & 63;
    const int wm   = (wave >> 1) * 64;
    const int wn   = (wave & 1) * 64;
    const int l16  = lane & 15;
    const int quad = lane >> 4;

    floatx4 acc[4][4] = {};

    // staging assignment: thread t loads 16 B (8 bf16) at row (t/8), kchunk (t%8)*8
    const int srow   = tid >> 3;          // 0..31
    const int kchunk = (tid & 7) * 8;     // element offset within BK row
    const __bf16* Ag = A + (size_t)(bm * BM + srow) * IN_TOT + kchunk;
    const __bf16* Wg = W + (size_t)(bn * BN + srow) * IN_TOT + kchunk;
    char* sAb = (char*)sA;
    char* sBb = (char*)sB;

    for (int k0 = 0; k0 < IN_TOT; k0 += BK) {
#pragma unroll
        for (int i = 0; i < 4; i++) {
            __builtin_amdgcn_global_load_lds(
                (__attribute__((address_space(1))) void*)(uintptr_t)(Ag + (size_t)i * 32 * IN_TOT + k0),
                (__attribute__((address_space(3))) void*)(sAb + i * 4096 + tid * 16),
                16, 0, 0);
            __builtin_amdgcn_global_load_lds(
                (__attribute__((address_space(1))) void*)(uintptr_t)(Wg + (size_t)i * 32 * IN_TOT + k0),
                (__attribute__((address_space(3))) void*)(sBb + i * 4096 + tid * 16),
                16, 0, 0);
        }
        __syncthreads();   // compiler emits vmcnt(0) drain before s_barrier

#pragma unroll
        for (int ks = 0; ks < 2; ks++) {
            bf16x8 af[4], bfr[4];
#pragma unroll
            for (int mi = 0; mi < 4; mi++)
                af[mi] = *(const bf16x8*)(sA + (wm + mi * 16 + l16) * BK + ks * 32 + quad * 8);
#pragma unroll
            for (int ni = 0; ni < 4; ni++)
                bfr[ni] = *(const bf16x8*)(sB + (wn + ni * 16 + l16) * BK + ks * 32 + quad * 8);
#pragma unroll
            for (int mi = 0; mi < 4; mi++)
#pragma unroll
                for (int ni = 0; ni < 4; ni++)
                    acc[mi][ni] = __builtin_amdgcn_mfma_f32_16x16x32_bf16(
                        af[mi], bfr[ni], acc[mi][ni], 0, 0, 0);
        }
        __syncthreads();
    }

    // epilogue: C/D layout col = lane&15, row = quad*4 + reg  [m89/m91 verified]
#pragma unroll
    for (int mi = 0; mi < 4; mi++) {
        int row = bm * BM + wm + mi * 16 + quad * 4;
#pragma unroll
        for (int ni = 0; ni < 4; ni++) {
            int col = bn * BN + wn + ni * 16 + l16;
            float bv = bias[col];
#pragma unroll
            for (int r = 0; r < 4; r++)
                C[(size_t)(row + r) * OUT_F + col] = acc[mi][ni][r] + bv;
        }
    }
}

// ---------------------------------------------------------------------------
// Launch
// ---------------------------------------------------------------------------
extern "C" void kernel_launch(void* const* d_in, const int* in_sizes, int n_in,
                              void* d_out, int out_size, void* d_ws, size_t ws_size,
                              hipStream_t stream) {
    const float* x      = (const float*)d_in[0];
    const float* w_vals = (const float*)d_in[1];
    const int*   w_rows = (const int*)  d_in[2];
    const int*   w_cols = (const int*)  d_in[3];
    const float* b_vals = (const float*)d_in[4];
    const int*   b_idx  = (const int*)  d_in[5];
    const float* e0v    = (const float*)d_in[6];
    const int*   e0p    = (const int*)  d_in[7];
    const float* e1v    = (const float*)d_in[8];
    const int*   e1p    = (const int*)  d_in[9];
    float* out = (float*)d_out;

    // workspace layout
    char* ws = (char*)d_ws;
    const size_t W_F32_BYTES  = (size_t)OUT_F * IN_TOT * 4;   // 17,825,792
    const size_t W_BF16_BYTES = (size_t)OUT_F * IN_TOT * 2;   //  8,912,896
    const size_t X_BF16_BYTES = (size_t)BATCH * IN_TOT * 2;   // 35,651,584
    float*  Wf = (float*)ws;
    __bf16* Wb = (__bf16*)(ws + W_F32_BYTES);
    __bf16* xb = (__bf16*)(ws + W_F32_BYTES + W_BF16_BYTES);
    float*  bf = (float*)(ws + W_F32_BYTES + W_BF16_BYTES + X_BF16_BYTES);

    // zero the scatter targets (ws is re-poisoned 0xAA before every launch)
    hipMemsetAsync(Wf, 0, W_F32_BYTES, stream);
    hipMemsetAsync(bf, 0, OUT_F * sizeof(float), stream);

    // build bf16 x_ext
    build_x_kernel<<<(BATCH * (IN_TOT / 4)) / 256, 256, 0, stream>>>(
        x, e0v, e0p, e1v, e1p, xb);

    // assemble W and b
    scatter_w_kernel<<<(NNZ_W + 255) / 256, 256, 0, stream>>>(w_vals, w_rows, w_cols, Wf);
    scatter_b_kernel<<<(NNZ_B + 255) / 256, 256, 0, stream>>>(b_vals, b_idx, bf);
    w_to_bf16_kernel<<<((size_t)OUT_F * IN_TOT / 4) / 256, 256, 0, stream>>>(Wf, Wb);

    // GEMM: out = xb @ Wb^T + bf
    dim3 grid(BATCH / BM, OUT_F / BN);
    gemm_kernel<<<grid, 256, 0, stream>>>(xb, Wb, bf, out);
}

// Round 2
// 251.196 us; speedup vs baseline: 1.0863x; 1.0863x over previous
//
#include <hip/hip_runtime.h>
#include <stdint.h>

#define OUT_F   2048
#define IN_BASE 2048
#define N_EMB   64
#define IN_TOT  2176   // 2048 + 128
#define NNZ_W   400000
#define NNZ_B   1024
#define BATCH   8192

typedef __bf16 bf16x8 __attribute__((ext_vector_type(8)));
typedef __bf16 bf16x4 __attribute__((ext_vector_type(4)));
typedef float  floatx4 __attribute__((ext_vector_type(4)));

// ---------------------------------------------------------------------------
// Kernel 1: build x_ext in bf16.  x_ext[b, 0:2048] = x, then
//   x_ext[b, 2048+j] = e0v[j] * x[b, e0p[j]]
//   x_ext[b, 2112+j] = e1v[j] * x_ext[b, e1p[j]]   (e1p < 2112, resolved inline)
// ---------------------------------------------------------------------------
__global__ void __launch_bounds__(256) build_x_kernel(
    const float* __restrict__ x,
    const float* __restrict__ e0v, const int* __restrict__ e0p,
    const float* __restrict__ e1v, const int* __restrict__ e1p,
    __bf16* __restrict__ xb)
{
    const int GROUPS = IN_TOT / 4;                 // 544 groups per row
    int gid = blockIdx.x * 256 + threadIdx.x;
    int b = gid / GROUPS;
    int g = gid - b * GROUPS;
    const float* xr = x + (size_t)b * IN_BASE;

    float v[4];
    if (g < IN_BASE / 4) {
        const float4 t = *(const float4*)(xr + g * 4);
        v[0] = t.x; v[1] = t.y; v[2] = t.z; v[3] = t.w;
    } else if (g < (IN_BASE + N_EMB) / 4) {        // embed0: cols 2048..2111
        int j = (g - IN_BASE / 4) * 4;
#pragma unroll
        for (int t = 0; t < 4; t++) v[t] = e0v[j + t] * xr[e0p[j + t]];
    } else {                                       // embed1: cols 2112..2175
        int j = (g - (IN_BASE + N_EMB) / 4) * 4;
#pragma unroll
        for (int t = 0; t < 4; t++) {
            int p = e1p[j + t];
            float base = (p < IN_BASE) ? xr[p]
                                       : e0v[p - IN_BASE] * xr[e0p[p - IN_BASE]];
            v[t] = e1v[j + t] * base;
        }
    }
    bf16x4 o;
    o[0] = (__bf16)v[0]; o[1] = (__bf16)v[1]; o[2] = (__bf16)v[2]; o[3] = (__bf16)v[3];
    *(bf16x4*)(xb + (size_t)b * IN_TOT + g * 4) = o;
}

// ---------------------------------------------------------------------------
// Kernel 2: fused COO scatter-add for W and bias (fp32 accumulate)
// ---------------------------------------------------------------------------
__global__ void __launch_bounds__(256) scatter_kernel(
    const float* __restrict__ wv, const int* __restrict__ wr,
    const int* __restrict__ wc,
    const float* __restrict__ bv, const int* __restrict__ bi,
    float* __restrict__ Wf, float* __restrict__ bf)
{
    int i = blockIdx.x * 256 + threadIdx.x;
    if (i < NNZ_W) {
        atomicAdd(Wf + (size_t)wr[i] * IN_TOT + wc[i], wv[i]);
    } else if (i < NNZ_W + NNZ_B) {
        int j = i - NNZ_W;
        atomicAdd(bf + bi[j], bv[j]);
    }
}

// ---------------------------------------------------------------------------
// Kernel 3: W fp32 -> bf16
// ---------------------------------------------------------------------------
__global__ void __launch_bounds__(256) w_to_bf16_kernel(
    const float* __restrict__ Wf, __bf16* __restrict__ Wb)
{
    int e = (blockIdx.x * 256 + threadIdx.x) * 4;
    const float4 t = *(const float4*)(Wf + e);
    bf16x4 o;
    o[0] = (__bf16)t.x; o[1] = (__bf16)t.y; o[2] = (__bf16)t.z; o[3] = (__bf16)t.w;
    *(bf16x4*)(Wb + e) = o;
}

// ---------------------------------------------------------------------------
// Kernel 4: GEMM  C[M,N] = A[M,K] * W[N,K]^T + bias   (K-major, "NT")
// 128x128 tile, 4 waves, 64x64/wave (4x4 of mfma_f32_16x16x32_bf16), BK=64,
// global_load_lds width=16 staging.
// LDS layout is XOR-swizzled at 16B granularity: chunk kc of row r lives at
// slot kc ^ (r & 7).  Staging realizes the swizzle on the GLOBAL side (lds
// dest is hardwired to base + lane*16); reads apply the inverse XOR, making
// each 8-lane b128 phase hit all 8 bank groups (conflict-free).
// ---------------------------------------------------------------------------
#define BM 128
#define BN 128
#define BK 64

__global__ void __launch_bounds__(256) gemm_kernel(
    const __bf16* __restrict__ A,   // [BATCH][IN_TOT]
    const __bf16* __restrict__ W,   // [OUT_F][IN_TOT]
    const float*  __restrict__ bias,
    float* __restrict__ C)          // [BATCH][OUT_F]
{
    __shared__ __bf16 sA[BM * BK];
    __shared__ __bf16 sB[BN * BK];

    const int tid  = threadIdx.x;
    const int bm   = blockIdx.x;    // M tile (64)
    const int bn   = blockIdx.y;    // N tile (16)
    const int wave = tid >> 6;
    const int lane = tid & 63;
    const int wm   = (wave >> 1) * 64;
    const int wn   = (wave & 1) * 64;
    const int l16  = lane & 15;
    const int quad = lane >> 4;

    floatx4 acc[4][4] = {};

    // staging: thread t -> LDS slot (row = t>>3, slot-chunk = t&7).
    // Swizzle: slot-chunk s of row r holds global chunk s ^ (r&7),
    // so the global chunk this thread fetches is (t&7) ^ ((t>>3)&7).
    const int srow   = tid >> 3;                              // 0..31
    const int kchunk = ((tid & 7) ^ ((tid >> 3) & 7)) * 8;    // element offset
    const __bf16* Ag = A + (size_t)(bm * BM + srow) * IN_TOT + kchunk;
    const __bf16* Wg = W + (size_t)(bn * BN + srow) * IN_TOT + kchunk;
    char* sAb = (char*)sA;
    char* sBb = (char*)sB;

    for (int k0 = 0; k0 < IN_TOT; k0 += BK) {
#pragma unroll
        for (int i = 0; i < 4; i++) {   // i*32 is 0 mod 8 -> same kchunk works
            __builtin_amdgcn_global_load_lds(
                (__attribute__((address_space(1))) void*)(uintptr_t)(Ag + (size_t)i * 32 * IN_TOT + k0),
                (__attribute__((address_space(3))) void*)(sAb + i * 4096 + tid * 16),
                16, 0, 0);
            __builtin_amdgcn_global_load_lds(
                (__attribute__((address_space(1))) void*)(uintptr_t)(Wg + (size_t)i * 32 * IN_TOT + k0),
                (__attribute__((address_space(3))) void*)(sBb + i * 4096 + tid * 16),
                16, 0, 0);
        }
        __syncthreads();

#pragma unroll
        for (int ks = 0; ks < 2; ks++) {
            bf16x8 af[4], bfr[4];
            // want chunk kc = ks*4 + quad of row; it lives at slot kc ^ (row&7),
            // row&7 == l16&7 (wm, mi*16 are multiples of 16)
            const int sl = ((ks * 4 + quad) ^ (l16 & 7)) * 8;  // element offset
#pragma unroll
            for (int mi = 0; mi < 4; mi++)
                af[mi] = *(const bf16x8*)(sA + (wm + mi * 16 + l16) * BK + sl);
#pragma unroll
            for (int ni = 0; ni < 4; ni++)
                bfr[ni] = *(const bf16x8*)(sB + (wn + ni * 16 + l16) * BK + sl);
#pragma unroll
            for (int mi = 0; mi < 4; mi++)
#pragma unroll
                for (int ni = 0; ni < 4; ni++)
                    acc[mi][ni] = __builtin_amdgcn_mfma_f32_16x16x32_bf16(
                        af[mi], bfr[ni], acc[mi][ni], 0, 0, 0);
        }
        __syncthreads();
    }

    // epilogue: C/D layout col = lane&15, row = quad*4 + reg  [m89/m91]
#pragma unroll
    for (int mi = 0; mi < 4; mi++) {
        int row = bm * BM + wm + mi * 16 + quad * 4;
#pragma unroll
        for (int ni = 0; ni < 4; ni++) {
            int col = bn * BN + wn + ni * 16 + l16;
            float bv = bias[col];
#pragma unroll
            for (int r = 0; r < 4; r++)
                C[(size_t)(row + r) * OUT_F + col] = acc[mi][ni][r] + bv;
        }
    }
}

// ---------------------------------------------------------------------------
// Launch
// ---------------------------------------------------------------------------
extern "C" void kernel_launch(void* const* d_in, const int* in_sizes, int n_in,
                              void* d_out, int out_size, void* d_ws, size_t ws_size,
                              hipStream_t stream) {
    const float* x      = (const float*)d_in[0];
    const float* w_vals = (const float*)d_in[1];
    const int*   w_rows = (const int*)  d_in[2];
    const int*   w_cols = (const int*)  d_in[3];
    const float* b_vals = (const float*)d_in[4];
    const int*   b_idx  = (const int*)  d_in[5];
    const float* e0v    = (const float*)d_in[6];
    const int*   e0p    = (const int*)  d_in[7];
    const float* e1v    = (const float*)d_in[8];
    const int*   e1p    = (const int*)  d_in[9];
    float* out = (float*)d_out;

    // workspace layout: Wf fp32 | bias fp32 (contiguous for single memset) | Wb | xb
    char* ws = (char*)d_ws;
    const size_t W_F32_BYTES  = (size_t)OUT_F * IN_TOT * 4;   // 17,825,792
    const size_t B_F32_BYTES  = (size_t)OUT_F * 4;            //      8,192
    const size_t W_BF16_BYTES = (size_t)OUT_F * IN_TOT * 2;   //  8,912,896
    float*  Wf = (float*)ws;
    float*  bf = (float*)(ws + W_F32_BYTES);
    __bf16* Wb = (__bf16*)(ws + W_F32_BYTES + B_F32_BYTES);
    __bf16* xb = (__bf16*)(ws + W_F32_BYTES + B_F32_BYTES + W_BF16_BYTES);

    // single memset covers Wf + bias
    hipMemsetAsync(Wf, 0, W_F32_BYTES + B_F32_BYTES, stream);

    build_x_kernel<<<(BATCH * (IN_TOT / 4)) / 256, 256, 0, stream>>>(
        x, e0v, e0p, e1v, e1p, xb);

    scatter_kernel<<<(NNZ_W + NNZ_B + 255) / 256, 256, 0, stream>>>(
        w_vals, w_rows, w_cols, b_vals, b_idx, Wf, bf);

    w_to_bf16_kernel<<<((size_t)OUT_F * IN_TOT / 4) / 256, 256, 0, stream>>>(Wf, Wb);

    dim3 grid(BATCH / BM, OUT_F / BN);
    gemm_kernel<<<grid, 256, 0, stream>>>(xb, Wb, bf, out);
}

// Round 3
// 248.322 us; speedup vs baseline: 1.0988x; 1.0116x over previous
//
#include <hip/hip_runtime.h>
#include <stdint.h>

#define OUT_F   2048
#define IN_BASE 2048
#define N_EMB   64
#define IN_TOT  2176   // 2048 + 128
#define NNZ_W   400000
#define NNZ_B   1024
#define BATCH   8192

typedef __bf16 bf16x8 __attribute__((ext_vector_type(8)));
typedef __bf16 bf16x4 __attribute__((ext_vector_type(4)));
typedef float  floatx16 __attribute__((ext_vector_type(16)));

// ---------------------------------------------------------------------------
// Kernel 1: build x_ext in bf16.  x_ext[b, 0:2048] = x, then
//   x_ext[b, 2048+j] = e0v[j] * x[b, e0p[j]]
//   x_ext[b, 2112+j] = e1v[j] * x_ext[b, e1p[j]]   (e1p < 2112, resolved inline)
// ---------------------------------------------------------------------------
__global__ void __launch_bounds__(256) build_x_kernel(
    const float* __restrict__ x,
    const float* __restrict__ e0v, const int* __restrict__ e0p,
    const float* __restrict__ e1v, const int* __restrict__ e1p,
    __bf16* __restrict__ xb)
{
    const int GROUPS = IN_TOT / 4;                 // 544 groups per row
    int gid = blockIdx.x * 256 + threadIdx.x;
    int b = gid / GROUPS;
    int g = gid - b * GROUPS;
    const float* xr = x + (size_t)b * IN_BASE;

    float v[4];
    if (g < IN_BASE / 4) {
        const float4 t = *(const float4*)(xr + g * 4);
        v[0] = t.x; v[1] = t.y; v[2] = t.z; v[3] = t.w;
    } else if (g < (IN_BASE + N_EMB) / 4) {        // embed0: cols 2048..2111
        int j = (g - IN_BASE / 4) * 4;
#pragma unroll
        for (int t = 0; t < 4; t++) v[t] = e0v[j + t] * xr[e0p[j + t]];
    } else {                                       // embed1: cols 2112..2175
        int j = (g - (IN_BASE + N_EMB) / 4) * 4;
#pragma unroll
        for (int t = 0; t < 4; t++) {
            int p = e1p[j + t];
            float base = (p < IN_BASE) ? xr[p]
                                       : e0v[p - IN_BASE] * xr[e0p[p - IN_BASE]];
            v[t] = e1v[j + t] * base;
        }
    }
    bf16x4 o;
    o[0] = (__bf16)v[0]; o[1] = (__bf16)v[1]; o[2] = (__bf16)v[2]; o[3] = (__bf16)v[3];
    *(bf16x4*)(xb + (size_t)b * IN_TOT + g * 4) = o;
}

// ---------------------------------------------------------------------------
// Kernel 2: fused COO scatter-add for W and bias (fp32 accumulate)
// ---------------------------------------------------------------------------
__global__ void __launch_bounds__(256) scatter_kernel(
    const float* __restrict__ wv, const int* __restrict__ wr,
    const int* __restrict__ wc,
    const float* __restrict__ bv, const int* __restrict__ bi,
    float* __restrict__ Wf, float* __restrict__ bf)
{
    int i = blockIdx.x * 256 + threadIdx.x;
    if (i < NNZ_W) {
        atomicAdd(Wf + (size_t)wr[i] * IN_TOT + wc[i], wv[i]);
    } else if (i < NNZ_W + NNZ_B) {
        int j = i - NNZ_W;
        atomicAdd(bf + bi[j], bv[j]);
    }
}

// ---------------------------------------------------------------------------
// Kernel 3: W fp32 -> bf16
// ---------------------------------------------------------------------------
__global__ void __launch_bounds__(256) w_to_bf16_kernel(
    const float* __restrict__ Wf, __bf16* __restrict__ Wb)
{
    int e = (blockIdx.x * 256 + threadIdx.x) * 4;
    const float4 t = *(const float4*)(Wf + e);
    bf16x4 o;
    o[0] = (__bf16)t.x; o[1] = (__bf16)t.y; o[2] = (__bf16)t.z; o[3] = (__bf16)t.w;
    *(bf16x4*)(Wb + e) = o;
}

// ---------------------------------------------------------------------------
// Kernel 4: GEMM  C[M,N] = A[M,K] * W[N,K]^T + bias   (K-major, "NT")
// 128x128 tile, 4 waves, 64x64/wave as 2x2 of mfma_f32_32x32x16_bf16, BK=64,
// global_load_lds width=16 staging.
// LDS layout XOR-swizzled at 16B granularity: chunk kc of row r lives at slot
// kc ^ (r & 7); swizzle realized on the GLOBAL side during staging (lds dest
// is hardwired to base + lane*16), inverse-XOR applied on read.
// 32x32x16 operand layout: A[m=lane&31][k=(lane>>5)*8+j] (8 contiguous K per
// lane, K-halves split at lane 32 — same grouping rule as verified 16x16x32);
// C/D: col=lane&31, row=(reg&3)+8*(reg>>2)+4*(lane>>5)  [m74/m101 verified].
// ---------------------------------------------------------------------------
#define BM 128
#define BN 128
#define BK 64

__global__ void __launch_bounds__(256) gemm_kernel(
    const __bf16* __restrict__ A,   // [BATCH][IN_TOT]
    const __bf16* __restrict__ W,   // [OUT_F][IN_TOT]
    const float*  __restrict__ bias,
    float* __restrict__ C)          // [BATCH][OUT_F]
{
    __shared__ __bf16 sA[BM * BK];
    __shared__ __bf16 sB[BN * BK];

    const int tid   = threadIdx.x;
    const int bm    = blockIdx.x;    // M tile (64)
    const int bn    = blockIdx.y;    // N tile (16)
    const int wave  = tid >> 6;
    const int lane  = tid & 63;
    const int wm    = (wave >> 1) * 64;
    const int wn    = (wave & 1) * 64;
    const int l32   = lane & 31;
    const int khalf = lane >> 5;

    floatx16 acc[2][2] = {};

    // staging: thread t -> LDS slot (row = t>>3, slot-chunk = t&7).
    // slot s of row r holds global chunk s ^ (r&7)  =>  fetch chunk (t&7)^((t>>3)&7)
    const int srow   = tid >> 3;                              // 0..31
    const int kchunk = ((tid & 7) ^ ((tid >> 3) & 7)) * 8;    // element offset
    const __bf16* Ag = A + (size_t)(bm * BM + srow) * IN_TOT + kchunk;
    const __bf16* Wg = W + (size_t)(bn * BN + srow) * IN_TOT + kchunk;
    char* sAb = (char*)sA;
    char* sBb = (char*)sB;

    for (int k0 = 0; k0 < IN_TOT; k0 += BK) {
#pragma unroll
        for (int i = 0; i < 4; i++) {
            __builtin_amdgcn_global_load_lds(
                (__attribute__((address_space(1))) void*)(uintptr_t)(Ag + (size_t)i * 32 * IN_TOT + k0),
                (__attribute__((address_space(3))) void*)(sAb + i * 4096 + tid * 16),
                16, 0, 0);
            __builtin_amdgcn_global_load_lds(
                (__attribute__((address_space(1))) void*)(uintptr_t)(Wg + (size_t)i * 32 * IN_TOT + k0),
                (__attribute__((address_space(3))) void*)(sBb + i * 4096 + tid * 16),
                16, 0, 0);
        }
        __syncthreads();

#pragma unroll
        for (int ks = 0; ks < 4; ks++) {          // K=16 per step
            // lane wants k = ks*16 + khalf*8 + j  ->  chunk kc = ks*2 + khalf,
            // stored at slot kc ^ (row&7), row&7 == l32&7
            const int sl = ((ks * 2 + khalf) ^ (l32 & 7)) * 8;  // element offset
            bf16x8 af[2], bfr[2];
#pragma unroll
            for (int mi = 0; mi < 2; mi++)
                af[mi] = *(const bf16x8*)(sA + (wm + mi * 32 + l32) * BK + sl);
#pragma unroll
            for (int ni = 0; ni < 2; ni++)
                bfr[ni] = *(const bf16x8*)(sB + (wn + ni * 32 + l32) * BK + sl);
#pragma unroll
            for (int mi = 0; mi < 2; mi++)
#pragma unroll
                for (int ni = 0; ni < 2; ni++)
                    acc[mi][ni] = __builtin_amdgcn_mfma_f32_32x32x16_bf16(
                        af[mi], bfr[ni], acc[mi][ni], 0, 0, 0);
        }
        __syncthreads();
    }

    // epilogue: C/D col = lane&31, row = (reg&3) + 8*(reg>>2) + 4*khalf
#pragma unroll
    for (int mi = 0; mi < 2; mi++) {
#pragma unroll
        for (int ni = 0; ni < 2; ni++) {
            const int colg = bn * BN + wn + ni * 32 + l32;
            const float bv = bias[colg];
            const int rowb = bm * BM + wm + mi * 32 + 4 * khalf;
#pragma unroll
            for (int reg = 0; reg < 16; reg++) {
                const int rowg = rowb + (reg & 3) + 8 * (reg >> 2);
                C[(size_t)rowg * OUT_F + colg] = acc[mi][ni][reg] + bv;
            }
        }
    }
}

// ---------------------------------------------------------------------------
// Launch
// ---------------------------------------------------------------------------
extern "C" void kernel_launch(void* const* d_in, const int* in_sizes, int n_in,
                              void* d_out, int out_size, void* d_ws, size_t ws_size,
                              hipStream_t stream) {
    const float* x      = (const float*)d_in[0];
    const float* w_vals = (const float*)d_in[1];
    const int*   w_rows = (const int*)  d_in[2];
    const int*   w_cols = (const int*)  d_in[3];
    const float* b_vals = (const float*)d_in[4];
    const int*   b_idx  = (const int*)  d_in[5];
    const float* e0v    = (const float*)d_in[6];
    const int*   e0p    = (const int*)  d_in[7];
    const float* e1v    = (const float*)d_in[8];
    const int*   e1p    = (const int*)  d_in[9];
    float* out = (float*)d_out;

    // workspace layout: Wf fp32 | bias fp32 (contiguous for single memset) | Wb | xb
    char* ws = (char*)d_ws;
    const size_t W_F32_BYTES  = (size_t)OUT_F * IN_TOT * 4;   // 17,825,792
    const size_t B_F32_BYTES  = (size_t)OUT_F * 4;            //      8,192
    const size_t W_BF16_BYTES = (size_t)OUT_F * IN_TOT * 2;   //  8,912,896
    float*  Wf = (float*)ws;
    float*  bf = (float*)(ws + W_F32_BYTES);
    __bf16* Wb = (__bf16*)(ws + W_F32_BYTES + B_F32_BYTES);
    __bf16* xb = (__bf16*)(ws + W_F32_BYTES + B_F32_BYTES + W_BF16_BYTES);

    // single memset covers Wf + bias
    hipMemsetAsync(Wf, 0, W_F32_BYTES + B_F32_BYTES, stream);

    build_x_kernel<<<(BATCH * (IN_TOT / 4)) / 256, 256, 0, stream>>>(
        x, e0v, e0p, e1v, e1p, xb);

    scatter_kernel<<<(NNZ_W + NNZ_B + 255) / 256, 256, 0, stream>>>(
        w_vals, w_rows, w_cols, b_vals, b_idx, Wf, bf);

    w_to_bf16_kernel<<<((size_t)OUT_F * IN_TOT / 4) / 256, 256, 0, stream>>>(Wf, Wb);

    dim3 grid(BATCH / BM, OUT_F / BN);
    gemm_kernel<<<grid, 256, 0, stream>>>(xb, Wb, bf, out);
}